// Round 1
// baseline (62.724 us; speedup 1.0000x reference)
//
#include <hip/hip_runtime.h>

#define BATCH 8
#define NATOM 256
#define DF    42
#define H1    64
#define H2    32

__device__ __forceinline__ float softplus_f(float z) {
  // numerically stable softplus
  return fmaxf(z, 0.f) + log1pf(expf(-fabsf(z)));
}

// ---------------- Kernel 1: per-atom mirrored MLP (fwd + analytic bwd) ----
// grid = B*N/4 blocks, 256 threads (4 waves). One wave per atom.
// lane h computes hidden unit h; cross-lane dot products via __shfl
// (compile-time lane index -> v_readlane). Weights staged to LDS in both
// orientations so every LDS read is lane-contiguous (conflict-free).
__global__ __launch_bounds__(256) void k1_mlp(
    const float* __restrict__ image,
    const float* __restrict__ W1, const float* __restrict__ b1,
    const float* __restrict__ W2, const float* __restrict__ b2,
    const float* __restrict__ W3, const float* __restrict__ b3,
    float* __restrict__ dG, float* __restrict__ Ei_ws) {
  __shared__ float sW1 [DF*H1];   // [d][h]
  __shared__ float sW1T[H1*DF];   // [h][d]
  __shared__ float sW2 [H1*H2];   // [h1][h2]
  __shared__ float sW2T[H2*H1];   // [h2][h1]
  __shared__ float sW3[H2], sb1[H1], sb2[H2];

  const int tid = threadIdx.x;
  for (int idx = tid; idx < DF*H1; idx += 256) {
    float w = W1[idx];
    sW1[idx] = w;
    sW1T[(idx & (H1-1))*DF + (idx >> 6)] = w;   // idx = d*64+h
  }
  for (int idx = tid; idx < H1*H2; idx += 256) {
    float w = W2[idx];
    sW2[idx] = w;
    sW2T[(idx & (H2-1))*H1 + (idx >> 5)] = w;   // idx = h1*32+h2
  }
  if (tid < H2)                    { sW3[tid] = W3[tid]; sb2[tid] = b2[tid]; }
  else if (tid >= 64 && tid < 128) { sb1[tid-64] = b1[tid-64]; }
  __syncthreads();

  const int lane = tid & 63;
  const int atom = blockIdx.x * 4 + (tid >> 6);      // 0..B*N-1

  // x in lanes 0..41
  float xv = (lane < DF) ? image[atom*DF + lane] : 0.f;

  // layer 1: z1[h] = b1[h] + sum_d x[d]*W1[d][h]   (lane = h)
  float z1 = sb1[lane];
  #pragma unroll
  for (int d = 0; d < DF; ++d)
    z1 = fmaf(__shfl(xv, d), sW1[d*H1 + lane], z1);
  float a1 = softplus_f(z1);

  // layer 2: lanes duplicated mod 32 (lane&31 = h2)
  const int h2l = lane & (H2-1);
  float z2 = sb2[h2l];
  #pragma unroll
  for (int h = 0; h < H1; ++h)
    z2 = fmaf(__shfl(a1, h), sW2[h*H2 + h2l], z2);
  float a2 = softplus_f(z2);

  // Ei = b3 + sum_h2 a2*W3 ;  g2 = sigmoid(z2)*W3 ; sigmoid(z)=1-exp(-softplus(z))
  float w3  = sW3[h2l];
  float eip = a2 * w3;
  #pragma unroll
  for (int off = 16; off; off >>= 1) eip += __shfl_xor(eip, off);  // sum within 32-group
  float g2 = (1.f - expf(-a2)) * w3;

  // g1[h] = sigmoid(z1[h]) * sum_h2 g2[h2]*W2[h][h2]
  float t1 = 0.f;
  #pragma unroll
  for (int h2 = 0; h2 < H2; ++h2)
    t1 = fmaf(__shfl(g2, h2), sW2T[h2*H1 + lane], t1);
  float g1 = (1.f - expf(-a1)) * t1;

  // dG[d] = sum_h g1[h]*W1[d][h]    (lane = d, lanes 0..41)
  const int dl = (lane < DF) ? lane : 0;
  float s = 0.f;
  #pragma unroll
  for (int h = 0; h < H1; ++h)
    s = fmaf(__shfl(g1, h), sW1T[h*DF + dl], s);

  if (lane < DF) dG[atom*DF + lane] = s;
  if (lane == 0) Ei_ws[atom] = eip + b3[0];
}

// ---------------- Kernel 2: Force[b,i,c] = sum_{j,f} dG[b,j,f]*dfeat[b,i,j,f,c]
// grid = B*N blocks (one per (b,i)), 256 threads.
// dG[b] (10752 floats, 43KB) staged in LDS. Each thread owns aligned groups
// of 12 consecutive floats of the dfeat row (= 4 complete (f,c) triples =
// 3 float4 loads + 1 ds_read_b128 of dG), so the c->accumulator mapping is
// fully static: 12 FMAs, no div/mod, no runtime-indexed arrays.
__global__ __launch_bounds__(256) void k2_force(
    const float* __restrict__ dfeat,
    const float* __restrict__ dG,
    const float* __restrict__ Ei_ws,
    float* __restrict__ out) {
  __shared__ float4 dg4[NATOM*DF/4];     // 2688 float4 = 43008 B
  __shared__ float red[4][3];
  __shared__ float ered[4];

  const int tid = threadIdx.x;
  const int bid = blockIdx.x;
  const int b = bid >> 8;           // batch
  const int i = bid & 255;          // atom i

  const float4* __restrict__ dgg = (const float4*)(dG + b*(NATOM*DF));
  for (int idx = tid; idx < NATOM*DF/4; idx += 256)
    dg4[idx] = dgg[idx];

  if (i == 0) {   // fold Etot[b] reduction into one block per batch
    float e = Ei_ws[b*NATOM + tid];
    #pragma unroll
    for (int off = 32; off; off >>= 1) e += __shfl_down(e, off);
    if ((tid & 63) == 0) ered[tid >> 6] = e;
  }
  __syncthreads();
  if (i == 0 && tid == 0) out[b] = ered[0] + ered[1] + ered[2] + ered[3];

  const float4* __restrict__ p4 =
      (const float4*)(dfeat + (size_t)bid * (NATOM*DF*3));

  float ax = 0.f, ay = 0.f, az = 0.f;
  // 2688 groups of 12 floats; group u: k = 4u..4u+3 (= j*DF+f), c pattern static
  for (int u = tid; u < NATOM*DF*3/12; u += 256) {
    float4 v0 = p4[3*u + 0];
    float4 v1 = p4[3*u + 1];
    float4 v2 = p4[3*u + 2];
    float4 g  = dg4[u];
    ax += g.x*v0.x + g.y*v0.w + g.z*v1.z + g.w*v2.y;
    ay += g.x*v0.y + g.y*v1.x + g.z*v1.w + g.w*v2.z;
    az += g.x*v0.z + g.y*v1.y + g.z*v2.x + g.w*v2.w;
  }

  #pragma unroll
  for (int off = 32; off; off >>= 1) {
    ax += __shfl_down(ax, off);
    ay += __shfl_down(ay, off);
    az += __shfl_down(az, off);
  }
  const int wv = tid >> 6;
  if ((tid & 63) == 0) { red[wv][0] = ax; red[wv][1] = ay; red[wv][2] = az; }
  __syncthreads();
  if (tid == 0) {
    out[BATCH + (size_t)bid*3 + 0] = red[0][0]+red[1][0]+red[2][0]+red[3][0];
    out[BATCH + (size_t)bid*3 + 1] = red[0][1]+red[1][1]+red[2][1]+red[3][1];
    out[BATCH + (size_t)bid*3 + 2] = red[0][2]+red[1][2]+red[2][2]+red[3][2];
  }
}

extern "C" void kernel_launch(void* const* d_in, const int* in_sizes, int n_in,
                              void* d_out, int out_size, void* d_ws, size_t ws_size,
                              hipStream_t stream) {
  const float* image = (const float*)d_in[0];
  const float* dfeat = (const float*)d_in[1];
  const float* W1    = (const float*)d_in[2];
  const float* b1    = (const float*)d_in[3];
  const float* W2    = (const float*)d_in[4];
  const float* b2    = (const float*)d_in[5];
  const float* W3    = (const float*)d_in[6];
  const float* b3    = (const float*)d_in[7];
  float* out = (float*)d_out;

  float* dG = (float*)d_ws;                       // B*N*DF floats
  float* Ei = dG + BATCH*NATOM*DF;                // B*N floats

  k1_mlp<<<BATCH*NATOM/4, 256, 0, stream>>>(image, W1, b1, W2, b2, W3, b3, dG, Ei);
  k2_force<<<BATCH*NATOM, 256, 0, stream>>>(dfeat, dG, Ei, out);
}